// Round 23
// baseline (683.857 us; speedup 1.0000x reference)
//
#include <hip/hip_runtime.h>
#include <math.h>

#define NPTS 100000
#define CCH 128
#define NWIN 200
#define NBLK_STATS 512
#define NBLK_SORT 391   // ceil(NPTS/256)
#define SEGSZ 128
#define NSEG_MAX 1024   // >= 200 + ceil(100000/128) = 982

#define BM 128
#define BN 128
#define BK 64

typedef __attribute__((ext_vector_type(8))) short bf16x8;
typedef __attribute__((ext_vector_type(4))) float f32x4;
typedef __attribute__((ext_vector_type(4))) unsigned short u16x4;

__device__ __forceinline__ unsigned short f2bf(float f) {
    union { float f; unsigned u; } x; x.f = f;
    unsigned r = x.u + 0x7fff + ((x.u >> 16) & 1);   // RNE (no NaN inputs here)
    return (unsigned short)(r >> 16);
}
__device__ __forceinline__ float bf2f(unsigned short h) {
    union { unsigned u; float f; } x; x.u = ((unsigned)h) << 16;
    return x.f;
}

// async global->LDS 16B: wave-uniform LDS base, per-lane global source
__device__ __forceinline__ void gload_lds16(const void* g, void* l) {
    __builtin_amdgcn_global_load_lds(
        (const __attribute__((address_space(1))) unsigned int*)g,
        (__attribute__((address_space(3))) unsigned int*)l, 16, 0, 0);
}

// ---------------- BN statistics: vectorized, 8 rows/block-pass ----------------
__global__ __launch_bounds__(256) void bn_partial(const float* __restrict__ F,
                                                  float* __restrict__ part) {
    int t = threadIdx.x;
    int b = blockIdx.x;
    int rg = t >> 5;            // row group 0..7
    int c4 = (t & 31) * 4;      // channel quad
    float s0=0.f,s1=0.f,s2=0.f,s3=0.f,q0=0.f,q1=0.f,q2=0.f,q3=0.f;
    for (int n = b * 8 + rg; n < NPTS; n += NBLK_STATS * 8) {
        float4 v = *reinterpret_cast<const float4*>(&F[(size_t)n * CCH + c4]);
        s0 += v.x; s1 += v.y; s2 += v.z; s3 += v.w;
        q0 += v.x*v.x; q1 += v.y*v.y; q2 += v.z*v.z; q3 += v.w*v.w;
    }
    __shared__ float red[8][256];
    red[rg][c4+0] = s0; red[rg][c4+1] = s1; red[rg][c4+2] = s2; red[rg][c4+3] = s3;
    red[rg][128+c4+0] = q0; red[rg][128+c4+1] = q1; red[rg][128+c4+2] = q2; red[rg][128+c4+3] = q3;
    __syncthreads();
    float a = 0.f;
#pragma unroll
    for (int g = 0; g < 8; g++) a += red[g][t];
    part[b * 256 + t] = a;
}

// ---------------- two-level partial reduce: 512 partials -> 16 ----------------
__global__ __launch_bounds__(256) void bnred_k(const float* __restrict__ part,
                                               float* __restrict__ part2) {
    int t = threadIdx.x;
    int i = blockIdx.x;     // 16 blocks
    float a = 0.f;
#pragma unroll 8
    for (int j = 0; j < 32; j++) a += part[(size_t)(i * 32 + j) * 256 + t];
    part2[i * 256 + t] = a;
}

__global__ void bn_finalize(const float* __restrict__ part2,
                            const float* __restrict__ g, const float* __restrict__ bb,
                            float* __restrict__ scale, float* __restrict__ shift) {
    int c = threadIdx.x;            // 128 threads
    double s = 0.0, q = 0.0;
#pragma unroll
    for (int b = 0; b < 16; b++) {
        s += (double)part2[b * 256 + c];
        q += (double)part2[b * 256 + 128 + c];
    }
    double m = s / (double)NPTS;
    double var = q / (double)NPTS - m * m;
    double rstd = 1.0 / sqrt(var + 1e-3);
    float sc = (float)rstd * g[c];
    scale[c] = sc;
    shift[c] = bb[c] - (float)m * sc;
}

// ---------------- W prep (GEMM weights) ----------------
__global__ __launch_bounds__(128) void wprep(
    const float* __restrict__ W, int K, int N,
    const float* __restrict__ sc, const float* __restrict__ sh,
    const float* __restrict__ bias,
    unsigned short* __restrict__ WT, float* __restrict__ biasf)
{
    int n = blockIdx.x;
    int t = threadIdx.x;
    float part = 0.f;
    for (int k = t; k < K; k += 128) {
        float w = W[(size_t)k * N + n];
        float s = sc ? sc[k] * w : w;
        WT[(size_t)n * K + k] = f2bf(s);
        if (sh) part += sh[k] * w;
    }
    __shared__ float red[128];
    red[t] = part;
    __syncthreads();
    for (int o = 64; o > 0; o >>= 1) {
        if (t < o) red[t] += red[t + o];
        __syncthreads();
    }
    if (t == 0) biasf[n] = red[0] + (bias ? bias[n] : 0.f);
}

// ---------------- conv W prep, all three convs in one: WB[tap][d][c] ----------------
__global__ void wconv_prep_all(const float* __restrict__ Wk, const float* __restrict__ Wh,
                               const float* __restrict__ Ww, unsigned short* __restrict__ WB) {
    int i = blockIdx.x * 256 + threadIdx.x;
    if (i >= 53 * 1024) return;
    int tap = i >> 10; int rem = i & 1023; int dd = rem >> 5; int c = rem & 31;
    const float* src; int lt;
    if (tap < 27)      { src = Wk; lt = tap; }
    else if (tap < 40) { src = Wh; lt = tap - 27; }
    else               { src = Ww; lt = tap - 40; }
    WB[i] = f2bf(src[lt * 1024 + c * 32 + dd]);
}

// ---------------- K=128 multi-N-tile GEMM, BM=64, async B-stage ----------------
template<int NT>
__global__ __launch_bounds__(256) void gemm_knt(
    const float* __restrict__ A, int lda,
    const unsigned short* __restrict__ WT, const float* __restrict__ biasf,
    unsigned short* __restrict__ Out, int ldo, int reluLim)
{
    __shared__ __align__(16) char smem[32768];
    unsigned short* As = (unsigned short*)smem;            // [64][128] bf16 (2 swizzled halves)
    unsigned short* Bs = (unsigned short*)(smem + 16384);  // [128][64] bf16
    unsigned short* Ep = (unsigned short*)(smem + 16384);  // [32][136] bf16 (aliases Bs)

    const int tid  = threadIdx.x;
    const int wave = tid >> 6;
    const int lane = tid & 63;
    const int bm = blockIdx.x * 64;
    const int lrow = lane & 15;
    const int lhk  = lane >> 4;

#pragma unroll
    for (int pass = 0; pass < 8; pass++) {
        int row = pass * 8 + (tid >> 5);
        int grow = bm + row;
        int c4 = (tid & 31) * 4;
        float4 v = make_float4(0.f, 0.f, 0.f, 0.f);
        if (grow < NPTS)
            v = *reinterpret_cast<const float4*>(&A[(size_t)grow * lda + c4]);
        u16x4 h4 = { f2bf(v.x), f2bf(v.y), f2bf(v.z), f2bf(v.w) };
        int half = c4 >> 6;
        int cw = c4 & 63;
        int sw = (cw >> 3) ^ (row & 7);
        *reinterpret_cast<u16x4*>(&As[row * 128 + half * 64 + sw * 8 + (cw & 7)]) = h4;
    }

    for (int nt = 0; nt < NT; nt++) {
        const int bn = nt * BN;
        f32x4 acc[8];
#pragma unroll
        for (int j = 0; j < 8; j++)
            acc[j] = (f32x4){0.f, 0.f, 0.f, 0.f};

#pragma unroll
        for (int h = 0; h < 2; h++) {
            __syncthreads();
            // ---- B stage: async global->LDS, linear dest, per-lane swizzled source ----
#pragma unroll
            for (int i = 0; i < 4; i++) {
                int s = (wave * 4 + i) * 64 + lane;   // granule 0..1023
                int n = s >> 3;
                int slot = s & 7;
                int ksl = slot ^ (n & 7);
                gload_lds16(&WT[(size_t)(bn + n) * 128 + h * 64 + ksl * 8],
                            (char*)Bs + (size_t)(wave * 4 + i) * 1024);
            }
            __syncthreads();
#pragma unroll
            for (int ks = 0; ks < 2; ks++) {
                bf16x8 af, bfr[8];
                {
                    int row = wave * 16 + lrow;
                    int sw = (ks * 4 + lhk) ^ (row & 7);
                    af = *reinterpret_cast<const bf16x8*>(&As[row * 128 + h * 64 + sw * 8]);
                }
#pragma unroll
                for (int fj = 0; fj < 8; fj++) {
                    int col = fj * 16 + lrow;
                    int sw = (ks * 4 + lhk) ^ (col & 7);
                    bfr[fj] = *reinterpret_cast<const bf16x8*>(&Bs[col * 64 + sw * 8]);
                }
#pragma unroll
                for (int fj = 0; fj < 8; fj++)
                    acc[fj] = __builtin_amdgcn_mfma_f32_16x16x32_bf16(
                        af, bfr[fj], acc[fj], 0, 0, 0);
            }
        }
        __syncthreads();   // Bs reads done -> Ep region free

        // ---- epilogue: bf16 Ep; 2 chunks of 32 rows, 2 waves fill each ----
#pragma unroll
        for (int ch = 0; ch < 2; ch++) {
            if ((wave >> 1) == ch) {
#pragma unroll
                for (int fj = 0; fj < 8; fj++) {
                    int col = fj * 16 + lrow;
                    float bv = biasf[bn + col];
                    bool rl = (bn + col) < reluLim;
#pragma unroll
                    for (int r = 0; r < 4; r++) {
                        int rloc = (wave & 1) * 16 + lhk * 4 + r;
                        float v = acc[fj][r] + bv;
                        if (rl) v = fmaxf(v, 0.f);
                        Ep[rloc * 136 + col] = f2bf(v);
                    }
                }
            }
            __syncthreads();
#pragma unroll
            for (int pass = 0; pass < 2; pass++) {
                int idx = pass * 256 + tid;     // 0..511
                int r = idx >> 4;               // 0..31
                int c8 = (idx & 15) * 8;        // 0..120
                int rr = bm + ch * 32 + r;
                if (rr < NPTS)
                    *reinterpret_cast<bf16x8*>(&Out[(size_t)rr * ldo + bn + c8]) =
                        *reinterpret_cast<const bf16x8*>(&Ep[r * 136 + c8]);
            }
            __syncthreads();
        }
    }
}

// ---------------- bf16 MFMA GEMM, BM=64, async B-stage (proj/fc2) ----------------
template<int ABF, int OBF>
__global__ __launch_bounds__(256) void gemm_t(
    const void* __restrict__ Ap, int lda,
    const unsigned short* __restrict__ WT, const float* __restrict__ biasf,
    int K,
    void* __restrict__ Outp, int ldo,
    int reluLim, int addFlag)
{
    __shared__ __align__(16) char smem[24576];
    unsigned short* As = (unsigned short*)smem;          // [64][64] bf16, swizzled
    unsigned short* Bs = (unsigned short*)(smem + 8192); // [128][64] bf16, swizzled
    float* Ep = (float*)smem;                            // [32][132] f32 (aliases all)

    const int tid  = threadIdx.x;
    const int wave = tid >> 6;
    const int lane = tid & 63;
    const int bm = blockIdx.y * 64;
    const int bn = blockIdx.x * BN;

    f32x4 acc[8];
#pragma unroll
    for (int j = 0; j < 8; j++)
        acc[j] = (f32x4){0.f, 0.f, 0.f, 0.f};

    const int lrow = lane & 15;
    const int lhk  = lane >> 4;           // 0..3

    for (int kk = 0; kk < K; kk += BK) {
        if (ABF) {
            const unsigned short* Ab = (const unsigned short*)Ap;
#pragma unroll
            for (int pass = 0; pass < 2; pass++) {
                int row = pass * 32 + (tid >> 3);
                int grow = bm + row;
                bf16x8 w = (bf16x8){0,0,0,0,0,0,0,0};
                if (grow < NPTS)
                    w = *reinterpret_cast<const bf16x8*>(&Ab[(size_t)grow * lda + kk + (tid & 7) * 8]);
                int sw = (tid & 7) ^ (row & 7);
                *reinterpret_cast<bf16x8*>(&As[row * 64 + sw * 8]) = w;
            }
        } else {
            const float* Af = (const float*)Ap;
#pragma unroll
            for (int pass = 0; pass < 4; pass++) {
                int row = pass * 16 + (tid >> 4);
                int grow = bm + row;
                int acol = (tid & 15) * 4;
                float4 v = make_float4(0.f, 0.f, 0.f, 0.f);
                if (grow < NPTS)
                    v = *reinterpret_cast<const float4*>(&Af[(size_t)grow * lda + kk + acol]);
                u16x4 h = { f2bf(v.x), f2bf(v.y), f2bf(v.z), f2bf(v.w) };
                int s = acol >> 3;
                int sw = s ^ (row & 7);
                *reinterpret_cast<u16x4*>(&As[row * 64 + sw * 8 + (acol & 7)]) = h;
            }
        }
        // ---- B stage: async global->LDS, linear dest, per-lane swizzled source ----
#pragma unroll
        for (int i = 0; i < 4; i++) {
            int s = (wave * 4 + i) * 64 + lane;   // granule 0..1023
            int n = s >> 3;
            int slot = s & 7;
            int ksl = slot ^ (n & 7);
            gload_lds16(&WT[(size_t)(bn + n) * K + kk + ksl * 8],
                        (char*)Bs + (size_t)(wave * 4 + i) * 1024);
        }
        __syncthreads();

#pragma unroll
        for (int ks = 0; ks < 2; ks++) {
            bf16x8 af, bfr[8];
            {
                int row = wave * 16 + lrow;
                int sw = (ks * 4 + lhk) ^ (row & 7);
                af = *reinterpret_cast<const bf16x8*>(&As[row * 64 + sw * 8]);
            }
#pragma unroll
            for (int fj = 0; fj < 8; fj++) {
                int col = fj * 16 + lrow;
                int sw = (ks * 4 + lhk) ^ (col & 7);
                bfr[fj] = *reinterpret_cast<const bf16x8*>(&Bs[col * 64 + sw * 8]);
            }
#pragma unroll
            for (int fj = 0; fj < 8; fj++)
                acc[fj] = __builtin_amdgcn_mfma_f32_16x16x32_bf16(
                    af, bfr[fj], acc[fj], 0, 0, 0);
        }
        __syncthreads();
    }

    // epilogue: 2 chunks of 32 rows; 2 waves fill each chunk concurrently
#pragma unroll
    for (int ch = 0; ch < 2; ch++) {
        if ((wave >> 1) == ch) {
#pragma unroll
            for (int fj = 0; fj < 8; fj++) {
                int col = fj * 16 + lrow;
#pragma unroll
                for (int r = 0; r < 4; r++) {
                    int rloc = (wave & 1) * 16 + lhk * 4 + r;
                    Ep[rloc * 132 + col] = acc[fj][r];
                }
            }
        }
        __syncthreads();
#pragma unroll
        for (int pass = 0; pass < 4; pass++) {
            int idx = pass * 256 + tid;     // 0..1023
            int r = idx >> 5;               // 0..31
            int c4 = (idx & 31) * 4;        // 0..124
            int rr = bm + ch * 32 + r;
            if (rr < NPTS) {
                float4 v = *reinterpret_cast<const float4*>(&Ep[r * 132 + c4]);
                float4 b = *reinterpret_cast<const float4*>(&biasf[bn + c4]);
                v.x += b.x; v.y += b.y; v.z += b.z; v.w += b.w;
                int col = bn + c4;
                if (col + 0 < reluLim) v.x = fmaxf(v.x, 0.f);
                if (col + 1 < reluLim) v.y = fmaxf(v.y, 0.f);
                if (col + 2 < reluLim) v.z = fmaxf(v.z, 0.f);
                if (col + 3 < reluLim) v.w = fmaxf(v.w, 0.f);
                if (OBF) {
                    unsigned short* o = (unsigned short*)Outp + (size_t)rr * ldo + bn + c4;
                    u16x4 hv = { f2bf(v.x), f2bf(v.y), f2bf(v.z), f2bf(v.w) };
                    *reinterpret_cast<u16x4*>(o) = hv;
                } else {
                    float* o = (float*)Outp + (size_t)rr * ldo + bn + c4;
                    if (addFlag) {
                        float4 ov = *reinterpret_cast<const float4*>(o);
                        v.x += ov.x; v.y += ov.y; v.z += ov.z; v.w += ov.w;
                    }
                    *reinterpret_cast<float4*>(o) = v;
                }
            }
        }
        __syncthreads();
    }
}

// ---------------- window histogram (per-block counts only) ----------------
__global__ __launch_bounds__(256) void hist2_k(const int* __restrict__ wi,
                                               int* __restrict__ BH) {
    __shared__ int h[NWIN];
    int t = threadIdx.x;
    if (t < NWIN) h[t] = 0;
    __syncthreads();
    int n = blockIdx.x * 256 + t;
    if (n < NPTS) atomicAdd(&h[wi[n]], 1);
    __syncthreads();
    if (t < NWIN) BH[blockIdx.x * 256 + t] = h[t];
}

// ---------------- parallel per-window scan of block counts ----------------
__global__ __launch_bounds__(256) void colscan2_k(const int* __restrict__ BH,
                                                  int* __restrict__ OFFB,
                                                  int* __restrict__ TOT) {
    int w = blockIdx.x;
    int t = threadIdx.x;
    __shared__ int s[512];
    int v0 = (t < NBLK_SORT) ? BH[t * 256 + w] : 0;
    int v1 = (t + 256 < NBLK_SORT) ? BH[(t + 256) * 256 + w] : 0;
    s[t] = v0; s[t + 256] = v1;
    __syncthreads();
#pragma unroll
    for (int off = 1; off < 512; off <<= 1) {
        int a0 = (t >= off) ? s[t - off] : 0;
        int a1 = (t + 256 >= off) ? s[t + 256 - off] : 0;
        __syncthreads();
        s[t] += a0;
        s[t + 256] += a1;
        __syncthreads();
    }
    if (t < NBLK_SORT) OFFB[t * 256 + w] = s[t] - v0;
    if (t + 256 < NBLK_SORT) OFFB[(t + 256) * 256 + w] = s[t + 256] - v1;
    if (t == 0) TOT[w] = s[NBLK_SORT - 1];
}

// ---------------- meta: window scan + segment build ----------------
__global__ __launch_bounds__(256) void meta2_k(const int* __restrict__ TOT,
                                               int* __restrict__ OFFS,
                                               int* __restrict__ SEGW, int* __restrict__ SEGP0,
                                               int* __restrict__ SEGP1, int* __restrict__ SEGBASE) {
    __shared__ int offs[NWIN + 1];
    __shared__ int segc[NWIN];
    int t = threadIdx.x;
    if (t < NWIN) segc[t] = TOT[t];
    __syncthreads();
    if (t == 0) {
        int a = 0;
        for (int w = 0; w < NWIN; w++) { int c = segc[w]; offs[w] = a; a += c; }
        offs[NWIN] = a;
    }
    __syncthreads();
    if (t <= NWIN) OFFS[t] = offs[t];
    if (t < NWIN) segc[t] = (offs[t + 1] - offs[t] + SEGSZ - 1) / SEGSZ;
    __syncthreads();
    if (t == 0) {
        int a = 0;
        for (int i = 0; i < NWIN; i++) { int c = segc[i]; segc[i] = a; SEGBASE[i] = a; a += c; }
        SEGBASE[NWIN] = a;
    }
    __syncthreads();
    if (t < NWIN) {
        int b = segc[t];
        int p0 = offs[t], p1 = offs[t + 1];
        for (int p = p0; p < p1; p += SEGSZ) {
            SEGW[b] = t; SEGP0[b] = p; SEGP1[b] = min(p + SEGSZ, p1); b++;
        }
    }
}

__global__ __launch_bounds__(256) void scatter2_k(const int* __restrict__ wi,
                                                  const int* __restrict__ OFFS,
                                                  const int* __restrict__ OFFB,
                                                  int* __restrict__ list) {
    __shared__ int h[NWIN];
    int t = threadIdx.x;
    if (t < NWIN) h[t] = 0;
    __syncthreads();
    int n = blockIdx.x * 256 + t;
    if (n < NPTS) {
        int w = wi[n];
        int r = atomicAdd(&h[w], 1);
        list[OFFS[w] + OFFB[blockIdx.x * 256 + w] + r] = n;
    }
}

// ---------------- per-segment K^T V and sum(K): bf16 in, register acc, plain stores ----------------
__global__ __launch_bounds__(256) void window_kv_seg(
    const unsigned short* __restrict__ R0bf,
    const int* __restrict__ list,
    const int* __restrict__ SEGP0, const int* __restrict__ SEGP1,
    const int* __restrict__ SEGBASE,
    float* __restrict__ PKV)
{
    int sid = blockIdx.x;
    if (sid >= SEGBASE[NWIN]) return;
    int t = threadIdx.x;
    int p0 = SEGP0[sid], p1 = SEGP1[sid];
    __shared__ float buf[8][256];   // [k(0..127) | v(128..255)]
    float acc[8] = {0.f,0.f,0.f,0.f,0.f,0.f,0.f,0.f};
    float sa = 0.f;
    int f0 = t * 8;
    int h = f0 >> 8;
    int c = (f0 >> 4) & 15;
    int d0 = f0 & 15;
    const int sr = t >> 5;          // staging row 0..7
    const int c8 = (t & 31) * 8;    // staging 8-col group

    for (int g = p0; g < p1; g += 8) {
        int m = min(8, p1 - g);
        int nj[8];
#pragma unroll
        for (int j = 0; j < 8; j++)
            nj[j] = list[(g + j < p1) ? g + j : p1 - 1];
        __syncthreads();   // buf free (previous group consumed)
        {
            const unsigned short* row = &R0bf[(size_t)nj[sr] * 384 + 128];
            bf16x8 hv = *reinterpret_cast<const bf16x8*>(&row[c8]);
            float4 lo = make_float4(bf2f((unsigned short)hv[0]), bf2f((unsigned short)hv[1]),
                                    bf2f((unsigned short)hv[2]), bf2f((unsigned short)hv[3]));
            float4 hi = make_float4(bf2f((unsigned short)hv[4]), bf2f((unsigned short)hv[5]),
                                    bf2f((unsigned short)hv[6]), bf2f((unsigned short)hv[7]));
            *reinterpret_cast<float4*>(&buf[sr][c8]) = lo;
            *reinterpret_cast<float4*>(&buf[sr][c8 + 4]) = hi;
        }
        __syncthreads();
#pragma unroll
        for (int j = 0; j < 8; j++) {
            if (j >= m) break;
            float kc = buf[j][h * 16 + c];
#pragma unroll
            for (int i = 0; i < 8; i++) acc[i] += kc * buf[j][128 + h * 16 + d0 + i];
            if (t < 128) sa += buf[j][t];
        }
    }
    float* out = &PKV[(size_t)sid * 2176];
#pragma unroll
    for (int i = 0; i < 8; i++) out[f0 + i] = acc[i];
    if (t < 128) out[2048 + t] = sa;
}

// ---------------- reduce segment partials per window ----------------
__global__ __launch_bounds__(256) void kv_reduce(
    const float* __restrict__ PKV, const int* __restrict__ SEGBASE,
    float* __restrict__ KV, float* __restrict__ SB)
{
    int w = blockIdx.x;
    int t = threadIdx.x;
    int s0 = SEGBASE[w], s1 = SEGBASE[w + 1];
    float a[8] = {0.f,0.f,0.f,0.f,0.f,0.f,0.f,0.f};
    float sb = 0.f;
    for (int s = s0; s < s1; s++) {
        const float* p = &PKV[(size_t)s * 2176];
#pragma unroll
        for (int i = 0; i < 8; i++) a[i] += p[t * 8 + i];
        if (t < 128) sb += p[2048 + t];
    }
#pragma unroll
    for (int i = 0; i < 8; i++) KV[w * 2048 + t * 8 + i] = a[i];
    if (t < 128) SB[w * 128 + t] = sb;
}

// ---------------- y = (q . kv[w]) / (q . s[w] + eps): bf16 q in, bf16 y out ----------------
__global__ __launch_bounds__(256) void attn_y_seg(
    const unsigned short* __restrict__ R0bf,
    unsigned short* __restrict__ Ybf,
    const int* __restrict__ list,
    const int* __restrict__ SEGW, const int* __restrict__ SEGP0,
    const int* __restrict__ SEGP1, const int* __restrict__ SEGBASE,
    const float* __restrict__ KV, const float* __restrict__ SB)
{
    int sid = blockIdx.x;
    if (sid >= SEGBASE[NWIN]) return;
    int t = threadIdx.x;
    int w = SEGW[sid];
    int g  = t >> 5;            // point group 0..7
    int h  = (t >> 2) & 7;      // head
    int d4 = (t & 3) * 4;       // output d offset

    float4 kvr[16];
    const float* kvb = &KV[w * 2048 + h * 256 + d4];
#pragma unroll
    for (int cc = 0; cc < 16; cc++)
        kvr[cc] = *reinterpret_cast<const float4*>(&kvb[cc * 16]);
    float sreg[16];
    const float* sb = &SB[w * 128 + h * 16];
#pragma unroll
    for (int cc = 0; cc < 16; cc++) sreg[cc] = sb[cc];

    int p0 = SEGP0[sid], p1 = SEGP1[sid];
    for (int p = p0 + g; p < p1; p += 8) {
        int n = list[p];
        const unsigned short* q = &R0bf[(size_t)n * 384 + h * 16];
        bf16x8 qa = *reinterpret_cast<const bf16x8*>(&q[0]);
        bf16x8 qb = *reinterpret_cast<const bf16x8*>(&q[8]);
        float qq[16];
#pragma unroll
        for (int i = 0; i < 8; i++) {
            qq[i] = bf2f((unsigned short)qa[i]);
            qq[8 + i] = bf2f((unsigned short)qb[i]);
        }
        float z = 0.f;
        float4 y = make_float4(0.f, 0.f, 0.f, 0.f);
#pragma unroll
        for (int cc = 0; cc < 16; cc++) {
            z += qq[cc] * sreg[cc];
            y.x += qq[cc] * kvr[cc].x;
            y.y += qq[cc] * kvr[cc].y;
            y.z += qq[cc] * kvr[cc].z;
            y.w += qq[cc] * kvr[cc].w;
        }
        float inv = 1.f / (z + 1e-3f);
        u16x4 o = { f2bf(y.x * inv), f2bf(y.y * inv), f2bf(y.z * inv), f2bf(y.w * inv) };
        *reinterpret_cast<u16x4*>(&Ybf[(size_t)n * 128 + h * 16 + d4]) = o;
    }
}

// ---------------- bn apply: FBbf = bf16(bn1(F)) (ld 128); F[:,96:128] = 2*bn1(F) ----------------
__global__ void bn_apply(float* F, unsigned short* __restrict__ FBbf,
                         const float* __restrict__ scale, const float* __restrict__ shift)
{
    int i = blockIdx.x * 256 + threadIdx.x;
    int n = i >> 5;
    int c4 = (i & 31) * 4;
    float4 v = *reinterpret_cast<const float4*>(&F[n * CCH + c4]);
    float4 o;
    o.x = v.x * scale[c4 + 0] + shift[c4 + 0];
    o.y = v.y * scale[c4 + 1] + shift[c4 + 1];
    o.z = v.z * scale[c4 + 2] + shift[c4 + 2];
    o.w = v.w * scale[c4 + 3] + shift[c4 + 3];
    u16x4 hv = { f2bf(o.x), f2bf(o.y), f2bf(o.z), f2bf(o.w) };
    *reinterpret_cast<u16x4*>(&FBbf[(size_t)n * 128 + c4]) = hv;
    if (c4 >= 96) {
        float4 t = make_float4(2.f * o.x, 2.f * o.y, 2.f * o.z, 2.f * o.w);
        *reinterpret_cast<float4*>(&F[n * CCH + c4]) = t;
    }
}

// ---------------- submanifold conv: direct-fragment gather, no staging barriers ----------------
template<int KN>
__global__ __launch_bounds__(256) void conv_direct(
    const int* __restrict__ nbrA, const int* __restrict__ nbrB,
    const unsigned short* __restrict__ WBall, int wbBase,
    const unsigned short* __restrict__ FBbf,
    float* __restrict__ F, int offBase)
{
    const int which = blockIdx.y;
    const int* __restrict__ nbr = which ? nbrB : nbrA;
    const int off = offBase + which * 32;
    const unsigned short* __restrict__ WB = WBall + wbBase + which * KN * 1024;

    __shared__ __align__(16) float Ep[128 * 36];

    const int tid = threadIdx.x;
    const int wave = tid >> 6;
    const int lane = tid & 63;
    const int bm = blockIdx.x * 128;
    const int lrow = lane & 15;
    const int lk = lane >> 4;       // 0..3

    const int row0 = bm + wave * 32 + lrow;
    const int row1 = row0 + 16;

    f32x4 acc[2][2];
#pragma unroll
    for (int i = 0; i < 2; i++)
#pragma unroll
        for (int j = 0; j < 2; j++)
            acc[i][j] = (f32x4){0.f, 0.f, 0.f, 0.f};

    constexpr int CHK = (KN == 27) ? 9 : 13;
    for (int c0 = 0; c0 < KN; c0 += CHK) {
        int i0[CHK], i1[CHK];
#pragma unroll
        for (int j = 0; j < CHK; j++) {
            i0[j] = (row0 < NPTS) ? nbr[(size_t)row0 * KN + c0 + j] : NPTS;
            i1[j] = (row1 < NPTS) ? nbr[(size_t)row1 * KN + c0 + j] : NPTS;
        }
#pragma unroll
        for (int j = 0; j < CHK; j++) {
            int k = c0 + j;
            bf16x8 a0 = (bf16x8){0,0,0,0,0,0,0,0};
            bf16x8 a1 = (bf16x8){0,0,0,0,0,0,0,0};
            if (i0[j] < NPTS)
                a0 = *reinterpret_cast<const bf16x8*>(&FBbf[(size_t)i0[j] * 128 + off + lk * 8]);
            if (i1[j] < NPTS)
                a1 = *reinterpret_cast<const bf16x8*>(&FBbf[(size_t)i1[j] * 128 + off + lk * 8]);
            bf16x8 b0 = *reinterpret_cast<const bf16x8*>(&WB[k * 1024 + lrow * 32 + lk * 8]);
            bf16x8 b1 = *reinterpret_cast<const bf16x8*>(&WB[k * 1024 + (16 + lrow) * 32 + lk * 8]);
            acc[0][0] = __builtin_amdgcn_mfma_f32_16x16x32_bf16(a0, b0, acc[0][0], 0, 0, 0);
            acc[0][1] = __builtin_amdgcn_mfma_f32_16x16x32_bf16(a0, b1, acc[0][1], 0, 0, 0);
            acc[1][0] = __builtin_amdgcn_mfma_f32_16x16x32_bf16(a1, b0, acc[1][0], 0, 0, 0);
            acc[1][1] = __builtin_amdgcn_mfma_f32_16x16x32_bf16(a1, b1, acc[1][1], 0, 0, 0);
        }
    }

    // epilogue: acc -> Ep [128 pts][32 ch pad 36] -> coalesced out with residual
#pragma unroll
    for (int fi = 0; fi < 2; fi++)
#pragma unroll
        for (int fj = 0; fj < 2; fj++) {
            int r0 = wave * 32 + fi * 16 + lk * 4;
            int col = fj * 16 + lrow;
#pragma unroll
            for (int r = 0; r < 4; r++)
                Ep[(r0 + r) * 36 + col] = acc[fi][fj][r];
        }
    __syncthreads();
#pragma unroll
    for (int pass = 0; pass < 4; pass++) {
        int idx = pass * 256 + tid;
        int r = idx >> 3;
        int c4 = (idx & 7) * 4;
        int rr = bm + r;
        if (rr < NPTS) {
            float4 v = *reinterpret_cast<const float4*>(&Ep[r * 36 + c4]);
            u16x4 fbh = *reinterpret_cast<const u16x4*>(&FBbf[(size_t)rr * 128 + off + c4]);
            v.x += bf2f(fbh.x); v.y += bf2f(fbh.y);
            v.z += bf2f(fbh.z); v.w += bf2f(fbh.w);
            *reinterpret_cast<float4*>(&F[(size_t)rr * CCH + off + c4]) = v;
        }
    }
}

// ---------------- launch ----------------
extern "C" void kernel_launch(void* const* d_in, const int* in_sizes, int n_in,
                              void* d_out, int out_size, void* d_ws, size_t ws_size,
                              hipStream_t stream)
{
    const float* feats   = (const float*)d_in[0];
    const int*   win_inds= (const int*)d_in[1];
    const int*   nbr_k   = (const int*)d_in[2];
    const int*   nbr_h   = (const int*)d_in[3];
    const int*   nbr_w   = (const int*)d_in[4];
    const float* bn_g    = (const float*)d_in[5];
    const float* bn_b    = (const float*)d_in[6];
    const float* Wqkv    = (const float*)d_in[7];
    const float* Wproj   = (const float*)d_in[8];
    const float* bproj   = (const float*)d_in[9];
    const float* bn1_g   = (const float*)d_in[10];
    const float* bn1_b   = (const float*)d_in[11];
    const float* Wk      = (const float*)d_in[12];
    const float* Wh      = (const float*)d_in[13];
    const float* Ww      = (const float*)d_in[14];
    const float* bn2_g   = (const float*)d_in[15];
    const float* bn2_b   = (const float*)d_in[16];
    const float* fc1_W   = (const float*)d_in[17];
    const float* fc1_b   = (const float*)d_in[18];
    const float* fc2_W   = (const float*)d_in[19];
    const float* fc2_b   = (const float*)d_in[20];

    float* F  = (float*)d_out;
    float* KV = (float*)d_ws;                       // NWIN*2048
    float* SB = KV + NWIN * 2048;                   // NWIN*128
    float* ST = SB + NWIN * 128;                    // 6*128
    float* PART = ST + 768;                         // NBLK_STATS*256
    float* PART2 = PART + NBLK_STATS * 256;         // 16*256
    float* PKV = PART2 + 16 * 256;                  // NSEG_MAX*2176
    int* OFFS = (int*)(PKV + (size_t)NSEG_MAX * 2176);  // 256 (201 used)
    int* TOT  = OFFS + 256;                         // 256
    int* LIST = TOT + 256;                          // 100096
    int* BH   = LIST + 100096;                      // NBLK_SORT*256
    int* OFFB = BH + NBLK_SORT * 256;               // NBLK_SORT*256
    int* SEGW = OFFB + NBLK_SORT * 256;             // NSEG_MAX
    int* SEGP0= SEGW + NSEG_MAX;                    // NSEG_MAX
    int* SEGP1= SEGP0 + NSEG_MAX;                   // NSEG_MAX
    int* SEGBASE = SEGP1 + NSEG_MAX;                // 256
    unsigned short* WQKVT = (unsigned short*)(SEGBASE + 256);   // 384*128
    unsigned short* WPROJT = WQKVT + 384 * 128;                 // 128*128
    unsigned short* WFC1T  = WPROJT + 128 * 128;                // 256*128
    unsigned short* WFC2T  = WFC1T + 256 * 128;                 // 128*256
    float* BQKV  = (float*)(WFC2T + 128 * 256);     // 384
    float* BPROJ = BQKV + 384;                      // 128
    float* BFC1  = BPROJ + 128;                     // 256
    float* BFC2  = BFC1 + 256;                      // 128
    unsigned short* R0bf = (unsigned short*)(BFC2 + 128);       // NPTS*384 bf16
    unsigned short* Hbf  = R0bf;                                // aliases (fc1 after R0bf dead)
    unsigned short* Ybf  = R0bf + (size_t)NPTS * 384;           // NPTS*128
    unsigned short* FBbf = Ybf + (size_t)NPTS * 128;            // NPTS*128
    unsigned short* WBall= FBbf + (size_t)NPTS * 128;           // 53*1024

    (void)hipMemcpyAsync(F, feats, (size_t)NPTS * CCH * sizeof(float),
                         hipMemcpyDeviceToDevice, stream);

    dim3 gr(1, 1563);                   // BM=64 residual GEMMs
    dim3 gc13(782, 2);                  // h/w convs

    for (int d = 0; d < 2; d++) {
        const int* wi = win_inds + (size_t)d * NPTS;
        float* SC0 = ST, *SH0 = ST + 128, *SC1 = ST + 256, *SH1 = ST + 384,
             * SC2 = ST + 512, *SH2 = ST + 640;

        // ---- BN0 stats + folded W ----
        bn_partial<<<NBLK_STATS, 256, 0, stream>>>(F, PART);
        bnred_k<<<16, 256, 0, stream>>>(PART, PART2);
        bn_finalize<<<1, 128, 0, stream>>>(PART2, bn_g + d * CCH, bn_b + d * CCH, SC0, SH0);
        wprep<<<384, 128, 0, stream>>>(Wqkv + (size_t)d * CCH * 384, 128, 384,
                                       SC0, SH0, nullptr, WQKVT, BQKV);
        wprep<<<128, 128, 0, stream>>>(Wproj + (size_t)d * CCH * CCH, 128, 128,
                                       nullptr, nullptr, bproj + d * CCH, WPROJT, BPROJ);
        wconv_prep_all<<<212, 256, 0, stream>>>(Wk + (size_t)d * 27 * 1024,
                                                Wh + (size_t)d * 13 * 1024,
                                                Ww + (size_t)d * 13 * 1024, WBall);

        // ---- [q|k|v] = bn0(F) @ Wqkv (relu on q,k) -> R0bf (bf16, ld 384); BM=64 ----
        gemm_knt<3><<<1563, 256, 0, stream>>>(F, CCH, WQKVT, BQKV, R0bf, 384, 256);

        // ---- window lists (counting sort; parallel scans) ----
        hist2_k<<<NBLK_SORT, 256, 0, stream>>>(wi, BH);
        colscan2_k<<<NWIN, 256, 0, stream>>>(BH, OFFB, TOT);
        meta2_k<<<1, 256, 0, stream>>>(TOT, OFFS, SEGW, SEGP0, SEGP1, SEGBASE);
        scatter2_k<<<NBLK_SORT, 256, 0, stream>>>(wi, OFFS, OFFB, LIST);

        // ---- per-segment KV partials + reduce ----
        window_kv_seg<<<NSEG_MAX, 256, 0, stream>>>(R0bf, LIST, SEGP0, SEGP1, SEGBASE, PKV);
        kv_reduce<<<NWIN, 256, 0, stream>>>(PKV, SEGBASE, KV, SB);

        // ---- y (bf16) ----
        attn_y_seg<<<NSEG_MAX, 256, 0, stream>>>(R0bf, Ybf, LIST, SEGW, SEGP0, SEGP1,
                                                 SEGBASE, KV, SB);

        // ---- F += y @ Wproj + bproj (BM=64) ----
        gemm_t<1,0><<<gr, 256, 0, stream>>>(Ybf, 128, WPROJT, BPROJ, 128,
                                            F, CCH, 0, 1);

        // ---- BN1 -> FBbf (bf16, ld 128), F[:,96:] = 2*bn1(F) ----
        bn_partial<<<NBLK_STATS, 256, 0, stream>>>(F, PART);
        bnred_k<<<16, 256, 0, stream>>>(PART, PART2);
        bn_finalize<<<1, 128, 0, stream>>>(PART2, bn1_g + d * CCH, bn1_b + d * CCH, SC1, SH1);
        bn_apply<<<12500, 256, 0, stream>>>(F, FBbf, SC1, SH1);

        // ---- submanifold convs: direct-fragment gather (residual fused) ----
        conv_direct<27><<<782, 256, 0, stream>>>(nbr_k, nbr_k, WBall, 0, FBbf, F, 0);
        conv_direct<13><<<gc13, 256, 0, stream>>>(nbr_h, nbr_w, WBall, 27 * 1024, FBbf, F, 32);

        // ---- BN2 stats + folded W for fc1; fc2 prep ----
        bn_partial<<<NBLK_STATS, 256, 0, stream>>>(F, PART);
        bnred_k<<<16, 256, 0, stream>>>(PART, PART2);
        bn_finalize<<<1, 128, 0, stream>>>(PART2, bn2_g + d * CCH, bn2_b + d * CCH, SC2, SH2);
        wprep<<<256, 128, 0, stream>>>(fc1_W + (size_t)d * CCH * 256, 128, 256,
                                       SC2, SH2, fc1_b + d * 256, WFC1T, BFC1);
        wprep<<<128, 128, 0, stream>>>(fc2_W + (size_t)d * 256 * CCH, 256, 128,
                                       nullptr, nullptr, fc2_b + d * CCH, WFC2T, BFC2);

        // ---- MLP: H = relu(bn2(F) @ fc1) (bf16, BM=64); F += H @ fc2 (BM=64) ----
        gemm_knt<2><<<1563, 256, 0, stream>>>(F, CCH, WFC1T, BFC1, Hbf, 256, 256);
        gemm_t<1,0><<<gr, 256, 0, stream>>>(Hbf, 256, WFC2T, BFC2, 256,
                                            F, CCH, 0, 1);
    }
}

// Round 24
// 676.420 us; speedup vs baseline: 1.0110x; 1.0110x over previous
//
#include <hip/hip_runtime.h>
#include <math.h>

#define NPTS 100000
#define CCH 128
#define NWIN 200
#define NBLK_STATS 512
#define NBLK_SORT 391   // ceil(NPTS/256)
#define SEGSZ 128
#define NSEG_MAX 1024   // >= 200 + ceil(100000/128) = 982

#define BM 128
#define BN 128
#define BK 64

typedef __attribute__((ext_vector_type(8))) short bf16x8;
typedef __attribute__((ext_vector_type(4))) float f32x4;
typedef __attribute__((ext_vector_type(4))) unsigned short u16x4;

__device__ __forceinline__ unsigned short f2bf(float f) {
    union { float f; unsigned u; } x; x.f = f;
    unsigned r = x.u + 0x7fff + ((x.u >> 16) & 1);   // RNE (no NaN inputs here)
    return (unsigned short)(r >> 16);
}
__device__ __forceinline__ float bf2f(unsigned short h) {
    union { unsigned u; float f; } x; x.u = ((unsigned)h) << 16;
    return x.f;
}

// ---------------- BN statistics: vectorized, 8 rows/block-pass ----------------
__global__ __launch_bounds__(256) void bn_partial(const float* __restrict__ F,
                                                  float* __restrict__ part) {
    int t = threadIdx.x;
    int b = blockIdx.x;
    int rg = t >> 5;            // row group 0..7
    int c4 = (t & 31) * 4;      // channel quad
    float s0=0.f,s1=0.f,s2=0.f,s3=0.f,q0=0.f,q1=0.f,q2=0.f,q3=0.f;
    for (int n = b * 8 + rg; n < NPTS; n += NBLK_STATS * 8) {
        float4 v = *reinterpret_cast<const float4*>(&F[(size_t)n * CCH + c4]);
        s0 += v.x; s1 += v.y; s2 += v.z; s3 += v.w;
        q0 += v.x*v.x; q1 += v.y*v.y; q2 += v.z*v.z; q3 += v.w*v.w;
    }
    __shared__ float red[8][256];
    red[rg][c4+0] = s0; red[rg][c4+1] = s1; red[rg][c4+2] = s2; red[rg][c4+3] = s3;
    red[rg][128+c4+0] = q0; red[rg][128+c4+1] = q1; red[rg][128+c4+2] = q2; red[rg][128+c4+3] = q3;
    __syncthreads();
    float a = 0.f;
#pragma unroll
    for (int g = 0; g < 8; g++) a += red[g][t];
    part[b * 256 + t] = a;
}

// ---------------- two-level partial reduce: 512 partials -> 16 ----------------
__global__ __launch_bounds__(256) void bnred_k(const float* __restrict__ part,
                                               float* __restrict__ part2) {
    int t = threadIdx.x;
    int i = blockIdx.x;     // 16 blocks
    float a = 0.f;
#pragma unroll 8
    for (int j = 0; j < 32; j++) a += part[(size_t)(i * 32 + j) * 256 + t];
    part2[i * 256 + t] = a;
}

__global__ void bn_finalize(const float* __restrict__ part2,
                            const float* __restrict__ g, const float* __restrict__ bb,
                            float* __restrict__ scale, float* __restrict__ shift) {
    int c = threadIdx.x;            // 128 threads
    double s = 0.0, q = 0.0;
#pragma unroll
    for (int b = 0; b < 16; b++) {
        s += (double)part2[b * 256 + c];
        q += (double)part2[b * 256 + 128 + c];
    }
    double m = s / (double)NPTS;
    double var = q / (double)NPTS - m * m;
    double rstd = 1.0 / sqrt(var + 1e-3);
    float sc = (float)rstd * g[c];
    scale[c] = sc;
    shift[c] = bb[c] - (float)m * sc;
}

// ---------------- W prep (GEMM weights) ----------------
__global__ __launch_bounds__(128) void wprep(
    const float* __restrict__ W, int K, int N,
    const float* __restrict__ sc, const float* __restrict__ sh,
    const float* __restrict__ bias,
    unsigned short* __restrict__ WT, float* __restrict__ biasf)
{
    int n = blockIdx.x;
    int t = threadIdx.x;
    float part = 0.f;
    for (int k = t; k < K; k += 128) {
        float w = W[(size_t)k * N + n];
        float s = sc ? sc[k] * w : w;
        WT[(size_t)n * K + k] = f2bf(s);
        if (sh) part += sh[k] * w;
    }
    __shared__ float red[128];
    red[t] = part;
    __syncthreads();
    for (int o = 64; o > 0; o >>= 1) {
        if (t < o) red[t] += red[t + o];
        __syncthreads();
    }
    if (t == 0) biasf[n] = red[0] + (bias ? bias[n] : 0.f);
}

// ---------------- conv W prep, all three convs in one: WB[tap][d][c] ----------------
__global__ void wconv_prep_all(const float* __restrict__ Wk, const float* __restrict__ Wh,
                               const float* __restrict__ Ww, unsigned short* __restrict__ WB) {
    int i = blockIdx.x * 256 + threadIdx.x;
    if (i >= 53 * 1024) return;
    int tap = i >> 10; int rem = i & 1023; int dd = rem >> 5; int c = rem & 31;
    const float* src; int lt;
    if (tap < 27)      { src = Wk; lt = tap; }
    else if (tap < 40) { src = Wh; lt = tap - 27; }
    else               { src = Ww; lt = tap - 40; }
    WB[i] = f2bf(src[lt * 1024 + c * 32 + dd]);
}

// ---------------- K=128 multi-N-tile GEMM, BM=64: 32768B LDS -> 5 blk/CU ----------------
// bf16 Ep epilogue: bias/relu/cvt in registers, Ep is a straight copy buffer.
template<int NT>
__global__ __launch_bounds__(256) void gemm_knt(
    const float* __restrict__ A, int lda,
    const unsigned short* __restrict__ WT, const float* __restrict__ biasf,
    unsigned short* __restrict__ Out, int ldo, int reluLim)
{
    __shared__ __align__(16) char smem[32768];
    unsigned short* As = (unsigned short*)smem;            // [64][128] bf16 (2 swizzled halves)
    unsigned short* Bs = (unsigned short*)(smem + 16384);  // [128][64] bf16
    unsigned short* Ep = (unsigned short*)(smem + 16384);  // [32][136] bf16 (aliases Bs)

    const int tid  = threadIdx.x;
    const int wave = tid >> 6;
    const int lane = tid & 63;
    const int bm = blockIdx.x * 64;
    const int lrow = lane & 15;
    const int lhk  = lane >> 4;

#pragma unroll
    for (int pass = 0; pass < 8; pass++) {
        int row = pass * 8 + (tid >> 5);
        int grow = bm + row;
        int c4 = (tid & 31) * 4;
        float4 v = make_float4(0.f, 0.f, 0.f, 0.f);
        if (grow < NPTS)
            v = *reinterpret_cast<const float4*>(&A[(size_t)grow * lda + c4]);
        u16x4 h4 = { f2bf(v.x), f2bf(v.y), f2bf(v.z), f2bf(v.w) };
        int half = c4 >> 6;
        int cw = c4 & 63;
        int sw = (cw >> 3) ^ (row & 7);
        *reinterpret_cast<u16x4*>(&As[row * 128 + half * 64 + sw * 8 + (cw & 7)]) = h4;
    }

    for (int nt = 0; nt < NT; nt++) {
        const int bn = nt * BN;
        f32x4 acc[8];
#pragma unroll
        for (int j = 0; j < 8; j++)
            acc[j] = (f32x4){0.f, 0.f, 0.f, 0.f};

#pragma unroll
        for (int h = 0; h < 2; h++) {
            __syncthreads();
#pragma unroll
            for (int pass = 0; pass < 4; pass++) {
                int n = pass * 32 + (tid >> 3);
                bf16x8 w = *reinterpret_cast<const bf16x8*>(
                    &WT[(size_t)(bn + n) * 128 + h * 64 + (tid & 7) * 8]);
                int sw = (tid & 7) ^ (n & 7);
                *reinterpret_cast<bf16x8*>(&Bs[n * 64 + sw * 8]) = w;
            }
            __syncthreads();
#pragma unroll
            for (int ks = 0; ks < 2; ks++) {
                bf16x8 af, bfr[8];
                {
                    int row = wave * 16 + lrow;
                    int sw = (ks * 4 + lhk) ^ (row & 7);
                    af = *reinterpret_cast<const bf16x8*>(&As[row * 128 + h * 64 + sw * 8]);
                }
#pragma unroll
                for (int fj = 0; fj < 8; fj++) {
                    int col = fj * 16 + lrow;
                    int sw = (ks * 4 + lhk) ^ (col & 7);
                    bfr[fj] = *reinterpret_cast<const bf16x8*>(&Bs[col * 64 + sw * 8]);
                }
#pragma unroll
                for (int fj = 0; fj < 8; fj++)
                    acc[fj] = __builtin_amdgcn_mfma_f32_16x16x32_bf16(
                        af, bfr[fj], acc[fj], 0, 0, 0);
            }
        }
        __syncthreads();   // Bs reads done -> Ep region free

        // ---- epilogue: bf16 Ep; 2 chunks of 32 rows, 2 waves fill each ----
#pragma unroll
        for (int ch = 0; ch < 2; ch++) {
            if ((wave >> 1) == ch) {
#pragma unroll
                for (int fj = 0; fj < 8; fj++) {
                    int col = fj * 16 + lrow;
                    float bv = biasf[bn + col];
                    bool rl = (bn + col) < reluLim;
#pragma unroll
                    for (int r = 0; r < 4; r++) {
                        int rloc = (wave & 1) * 16 + lhk * 4 + r;
                        float v = acc[fj][r] + bv;
                        if (rl) v = fmaxf(v, 0.f);
                        Ep[rloc * 136 + col] = f2bf(v);
                    }
                }
            }
            __syncthreads();
#pragma unroll
            for (int pass = 0; pass < 2; pass++) {
                int idx = pass * 256 + tid;     // 0..511
                int r = idx >> 4;               // 0..31
                int c8 = (idx & 15) * 8;        // 0..120
                int rr = bm + ch * 32 + r;
                if (rr < NPTS)
                    *reinterpret_cast<bf16x8*>(&Out[(size_t)rr * ldo + bn + c8]) =
                        *reinterpret_cast<const bf16x8*>(&Ep[r * 136 + c8]);
            }
            __syncthreads();
        }
    }
}

// ---------------- bf16 MFMA GEMM, BM=64 (proj/fc2: bf16 A, f32 out + residual) ----------------
template<int ABF, int OBF>
__global__ __launch_bounds__(256) void gemm_t(
    const void* __restrict__ Ap, int lda,
    const unsigned short* __restrict__ WT, const float* __restrict__ biasf,
    int K,
    void* __restrict__ Outp, int ldo,
    int reluLim, int addFlag)
{
    __shared__ __align__(16) char smem[24576];
    unsigned short* As = (unsigned short*)smem;          // [64][64] bf16, swizzled
    unsigned short* Bs = (unsigned short*)(smem + 8192); // [128][64] bf16, swizzled
    float* Ep = (float*)smem;                            // [32][132] f32 (aliases all)

    const int tid  = threadIdx.x;
    const int wave = tid >> 6;
    const int lane = tid & 63;
    const int bm = blockIdx.y * 64;
    const int bn = blockIdx.x * BN;

    f32x4 acc[8];
#pragma unroll
    for (int j = 0; j < 8; j++)
        acc[j] = (f32x4){0.f, 0.f, 0.f, 0.f};

    const int lrow = lane & 15;
    const int lhk  = lane >> 4;           // 0..3

    for (int kk = 0; kk < K; kk += BK) {
        if (ABF) {
            const unsigned short* Ab = (const unsigned short*)Ap;
#pragma unroll
            for (int pass = 0; pass < 2; pass++) {
                int row = pass * 32 + (tid >> 3);
                int grow = bm + row;
                bf16x8 w = (bf16x8){0,0,0,0,0,0,0,0};
                if (grow < NPTS)
                    w = *reinterpret_cast<const bf16x8*>(&Ab[(size_t)grow * lda + kk + (tid & 7) * 8]);
                int sw = (tid & 7) ^ (row & 7);
                *reinterpret_cast<bf16x8*>(&As[row * 64 + sw * 8]) = w;
            }
        } else {
            const float* Af = (const float*)Ap;
#pragma unroll
            for (int pass = 0; pass < 4; pass++) {
                int row = pass * 16 + (tid >> 4);
                int grow = bm + row;
                int acol = (tid & 15) * 4;
                float4 v = make_float4(0.f, 0.f, 0.f, 0.f);
                if (grow < NPTS)
                    v = *reinterpret_cast<const float4*>(&Af[(size_t)grow * lda + kk + acol]);
                u16x4 h = { f2bf(v.x), f2bf(v.y), f2bf(v.z), f2bf(v.w) };
                int s = acol >> 3;
                int sw = s ^ (row & 7);
                *reinterpret_cast<u16x4*>(&As[row * 64 + sw * 8 + (acol & 7)]) = h;
            }
        }
#pragma unroll
        for (int pass = 0; pass < 4; pass++) {
            int n = pass * 32 + (tid >> 3);
            bf16x8 w = *reinterpret_cast<const bf16x8*>(&WT[(size_t)(bn + n) * K + kk + (tid & 7) * 8]);
            int sw = (tid & 7) ^ (n & 7);
            *reinterpret_cast<bf16x8*>(&Bs[n * 64 + sw * 8]) = w;
        }
        __syncthreads();

#pragma unroll
        for (int ks = 0; ks < 2; ks++) {
            bf16x8 af, bfr[8];
            {
                int row = wave * 16 + lrow;
                int sw = (ks * 4 + lhk) ^ (row & 7);
                af = *reinterpret_cast<const bf16x8*>(&As[row * 64 + sw * 8]);
            }
#pragma unroll
            for (int fj = 0; fj < 8; fj++) {
                int col = fj * 16 + lrow;
                int sw = (ks * 4 + lhk) ^ (col & 7);
                bfr[fj] = *reinterpret_cast<const bf16x8*>(&Bs[col * 64 + sw * 8]);
            }
#pragma unroll
            for (int fj = 0; fj < 8; fj++)
                acc[fj] = __builtin_amdgcn_mfma_f32_16x16x32_bf16(
                    af, bfr[fj], acc[fj], 0, 0, 0);
        }
        __syncthreads();
    }

    // epilogue: 2 chunks of 32 rows; 2 waves fill each chunk concurrently
#pragma unroll
    for (int ch = 0; ch < 2; ch++) {
        if ((wave >> 1) == ch) {
#pragma unroll
            for (int fj = 0; fj < 8; fj++) {
                int col = fj * 16 + lrow;
#pragma unroll
                for (int r = 0; r < 4; r++) {
                    int rloc = (wave & 1) * 16 + lhk * 4 + r;
                    Ep[rloc * 132 + col] = acc[fj][r];
                }
            }
        }
        __syncthreads();
#pragma unroll
        for (int pass = 0; pass < 4; pass++) {
            int idx = pass * 256 + tid;     // 0..1023
            int r = idx >> 5;               // 0..31
            int c4 = (idx & 31) * 4;        // 0..124
            int rr = bm + ch * 32 + r;
            if (rr < NPTS) {
                float4 v = *reinterpret_cast<const float4*>(&Ep[r * 132 + c4]);
                float4 b = *reinterpret_cast<const float4*>(&biasf[bn + c4]);
                v.x += b.x; v.y += b.y; v.z += b.z; v.w += b.w;
                int col = bn + c4;
                if (col + 0 < reluLim) v.x = fmaxf(v.x, 0.f);
                if (col + 1 < reluLim) v.y = fmaxf(v.y, 0.f);
                if (col + 2 < reluLim) v.z = fmaxf(v.z, 0.f);
                if (col + 3 < reluLim) v.w = fmaxf(v.w, 0.f);
                if (OBF) {
                    unsigned short* o = (unsigned short*)Outp + (size_t)rr * ldo + bn + c4;
                    u16x4 hv = { f2bf(v.x), f2bf(v.y), f2bf(v.z), f2bf(v.w) };
                    *reinterpret_cast<u16x4*>(o) = hv;
                } else {
                    float* o = (float*)Outp + (size_t)rr * ldo + bn + c4;
                    if (addFlag) {
                        float4 ov = *reinterpret_cast<const float4*>(o);
                        v.x += ov.x; v.y += ov.y; v.z += ov.z; v.w += ov.w;
                    }
                    *reinterpret_cast<float4*>(o) = v;
                }
            }
        }
        __syncthreads();
    }
}

// ---------------- window histogram (per-block counts only) ----------------
__global__ __launch_bounds__(256) void hist2_k(const int* __restrict__ wi,
                                               int* __restrict__ BH) {
    __shared__ int h[NWIN];
    int t = threadIdx.x;
    if (t < NWIN) h[t] = 0;
    __syncthreads();
    int n = blockIdx.x * 256 + t;
    if (n < NPTS) atomicAdd(&h[wi[n]], 1);
    __syncthreads();
    if (t < NWIN) BH[blockIdx.x * 256 + t] = h[t];
}

// ---------------- parallel per-window scan of block counts ----------------
__global__ __launch_bounds__(256) void colscan2_k(const int* __restrict__ BH,
                                                  int* __restrict__ OFFB,
                                                  int* __restrict__ TOT) {
    int w = blockIdx.x;
    int t = threadIdx.x;
    __shared__ int s[512];
    int v0 = (t < NBLK_SORT) ? BH[t * 256 + w] : 0;
    int v1 = (t + 256 < NBLK_SORT) ? BH[(t + 256) * 256 + w] : 0;
    s[t] = v0; s[t + 256] = v1;
    __syncthreads();
#pragma unroll
    for (int off = 1; off < 512; off <<= 1) {
        int a0 = (t >= off) ? s[t - off] : 0;
        int a1 = (t + 256 >= off) ? s[t + 256 - off] : 0;
        __syncthreads();
        s[t] += a0;
        s[t + 256] += a1;
        __syncthreads();
    }
    if (t < NBLK_SORT) OFFB[t * 256 + w] = s[t] - v0;
    if (t + 256 < NBLK_SORT) OFFB[(t + 256) * 256 + w] = s[t + 256] - v1;
    if (t == 0) TOT[w] = s[NBLK_SORT - 1];
}

// ---------------- meta: window scan + segment build ----------------
__global__ __launch_bounds__(256) void meta2_k(const int* __restrict__ TOT,
                                               int* __restrict__ OFFS,
                                               int* __restrict__ SEGW, int* __restrict__ SEGP0,
                                               int* __restrict__ SEGP1, int* __restrict__ SEGBASE) {
    __shared__ int offs[NWIN + 1];
    __shared__ int segc[NWIN];
    int t = threadIdx.x;
    if (t < NWIN) segc[t] = TOT[t];
    __syncthreads();
    if (t == 0) {
        int a = 0;
        for (int w = 0; w < NWIN; w++) { int c = segc[w]; offs[w] = a; a += c; }
        offs[NWIN] = a;
    }
    __syncthreads();
    if (t <= NWIN) OFFS[t] = offs[t];
    if (t < NWIN) segc[t] = (offs[t + 1] - offs[t] + SEGSZ - 1) / SEGSZ;
    __syncthreads();
    if (t == 0) {
        int a = 0;
        for (int i = 0; i < NWIN; i++) { int c = segc[i]; segc[i] = a; SEGBASE[i] = a; a += c; }
        SEGBASE[NWIN] = a;
    }
    __syncthreads();
    if (t < NWIN) {
        int b = segc[t];
        int p0 = offs[t], p1 = offs[t + 1];
        for (int p = p0; p < p1; p += SEGSZ) {
            SEGW[b] = t; SEGP0[b] = p; SEGP1[b] = min(p + SEGSZ, p1); b++;
        }
    }
}

__global__ __launch_bounds__(256) void scatter2_k(const int* __restrict__ wi,
                                                  const int* __restrict__ OFFS,
                                                  const int* __restrict__ OFFB,
                                                  int* __restrict__ list) {
    __shared__ int h[NWIN];
    int t = threadIdx.x;
    if (t < NWIN) h[t] = 0;
    __syncthreads();
    int n = blockIdx.x * 256 + t;
    if (n < NPTS) {
        int w = wi[n];
        int r = atomicAdd(&h[w], 1);
        list[OFFS[w] + OFFB[blockIdx.x * 256 + w] + r] = n;
    }
}

// ---------------- per-segment K^T V and sum(K): bf16 in, register acc, plain stores ----------------
__global__ __launch_bounds__(256) void window_kv_seg(
    const unsigned short* __restrict__ R0bf,
    const int* __restrict__ list,
    const int* __restrict__ SEGP0, const int* __restrict__ SEGP1,
    const int* __restrict__ SEGBASE,
    float* __restrict__ PKV)
{
    int sid = blockIdx.x;
    if (sid >= SEGBASE[NWIN]) return;
    int t = threadIdx.x;
    int p0 = SEGP0[sid], p1 = SEGP1[sid];
    __shared__ float buf[8][256];   // [k(0..127) | v(128..255)]
    float acc[8] = {0.f,0.f,0.f,0.f,0.f,0.f,0.f,0.f};
    float sa = 0.f;
    int f0 = t * 8;
    int h = f0 >> 8;
    int c = (f0 >> 4) & 15;
    int d0 = f0 & 15;
    const int sr = t >> 5;          // staging row 0..7
    const int c8 = (t & 31) * 8;    // staging 8-col group

    for (int g = p0; g < p1; g += 8) {
        int m = min(8, p1 - g);
        int nj[8];
#pragma unroll
        for (int j = 0; j < 8; j++)
            nj[j] = list[(g + j < p1) ? g + j : p1 - 1];
        __syncthreads();   // buf free (previous group consumed)
        {
            const unsigned short* row = &R0bf[(size_t)nj[sr] * 384 + 128];
            bf16x8 hv = *reinterpret_cast<const bf16x8*>(&row[c8]);
            float4 lo = make_float4(bf2f((unsigned short)hv[0]), bf2f((unsigned short)hv[1]),
                                    bf2f((unsigned short)hv[2]), bf2f((unsigned short)hv[3]));
            float4 hi = make_float4(bf2f((unsigned short)hv[4]), bf2f((unsigned short)hv[5]),
                                    bf2f((unsigned short)hv[6]), bf2f((unsigned short)hv[7]));
            *reinterpret_cast<float4*>(&buf[sr][c8]) = lo;
            *reinterpret_cast<float4*>(&buf[sr][c8 + 4]) = hi;
        }
        __syncthreads();
#pragma unroll
        for (int j = 0; j < 8; j++) {
            if (j >= m) break;
            float kc = buf[j][h * 16 + c];
#pragma unroll
            for (int i = 0; i < 8; i++) acc[i] += kc * buf[j][128 + h * 16 + d0 + i];
            if (t < 128) sa += buf[j][t];
        }
    }
    float* out = &PKV[(size_t)sid * 2176];
#pragma unroll
    for (int i = 0; i < 8; i++) out[f0 + i] = acc[i];
    if (t < 128) out[2048 + t] = sa;
}

// ---------------- reduce segment partials per window ----------------
__global__ __launch_bounds__(256) void kv_reduce(
    const float* __restrict__ PKV, const int* __restrict__ SEGBASE,
    float* __restrict__ KV, float* __restrict__ SB)
{
    int w = blockIdx.x;
    int t = threadIdx.x;
    int s0 = SEGBASE[w], s1 = SEGBASE[w + 1];
    float a[8] = {0.f,0.f,0.f,0.f,0.f,0.f,0.f,0.f};
    float sb = 0.f;
    for (int s = s0; s < s1; s++) {
        const float* p = &PKV[(size_t)s * 2176];
#pragma unroll
        for (int i = 0; i < 8; i++) a[i] += p[t * 8 + i];
        if (t < 128) sb += p[2048 + t];
    }
#pragma unroll
    for (int i = 0; i < 8; i++) KV[w * 2048 + t * 8 + i] = a[i];
    if (t < 128) SB[w * 128 + t] = sb;
}

// ---------------- y = (q . kv[w]) / (q . s[w] + eps): bf16 q in, bf16 y out ----------------
__global__ __launch_bounds__(256) void attn_y_seg(
    const unsigned short* __restrict__ R0bf,
    unsigned short* __restrict__ Ybf,
    const int* __restrict__ list,
    const int* __restrict__ SEGW, const int* __restrict__ SEGP0,
    const int* __restrict__ SEGP1, const int* __restrict__ SEGBASE,
    const float* __restrict__ KV, const float* __restrict__ SB)
{
    int sid = blockIdx.x;
    if (sid >= SEGBASE[NWIN]) return;
    int t = threadIdx.x;
    int w = SEGW[sid];
    int g  = t >> 5;            // point group 0..7
    int h  = (t >> 2) & 7;      // head
    int d4 = (t & 3) * 4;       // output d offset

    float4 kvr[16];
    const float* kvb = &KV[w * 2048 + h * 256 + d4];
#pragma unroll
    for (int cc = 0; cc < 16; cc++)
        kvr[cc] = *reinterpret_cast<const float4*>(&kvb[cc * 16]);
    float sreg[16];
    const float* sb = &SB[w * 128 + h * 16];
#pragma unroll
    for (int cc = 0; cc < 16; cc++) sreg[cc] = sb[cc];

    int p0 = SEGP0[sid], p1 = SEGP1[sid];
    for (int p = p0 + g; p < p1; p += 8) {
        int n = list[p];
        const unsigned short* q = &R0bf[(size_t)n * 384 + h * 16];
        bf16x8 qa = *reinterpret_cast<const bf16x8*>(&q[0]);
        bf16x8 qb = *reinterpret_cast<const bf16x8*>(&q[8]);
        float qq[16];
#pragma unroll
        for (int i = 0; i < 8; i++) {
            qq[i] = bf2f((unsigned short)qa[i]);
            qq[8 + i] = bf2f((unsigned short)qb[i]);
        }
        float z = 0.f;
        float4 y = make_float4(0.f, 0.f, 0.f, 0.f);
#pragma unroll
        for (int cc = 0; cc < 16; cc++) {
            z += qq[cc] * sreg[cc];
            y.x += qq[cc] * kvr[cc].x;
            y.y += qq[cc] * kvr[cc].y;
            y.z += qq[cc] * kvr[cc].z;
            y.w += qq[cc] * kvr[cc].w;
        }
        float inv = 1.f / (z + 1e-3f);
        u16x4 o = { f2bf(y.x * inv), f2bf(y.y * inv), f2bf(y.z * inv), f2bf(y.w * inv) };
        *reinterpret_cast<u16x4*>(&Ybf[(size_t)n * 128 + h * 16 + d4]) = o;
    }
}

// ---------------- bn apply: FBbf = bf16(bn1(F)) (ld 128); F[:,96:128] = 2*bn1(F) ----------------
__global__ void bn_apply(float* F, unsigned short* __restrict__ FBbf,
                         const float* __restrict__ scale, const float* __restrict__ shift)
{
    int i = blockIdx.x * 256 + threadIdx.x;
    int n = i >> 5;
    int c4 = (i & 31) * 4;
    float4 v = *reinterpret_cast<const float4*>(&F[n * CCH + c4]);
    float4 o;
    o.x = v.x * scale[c4 + 0] + shift[c4 + 0];
    o.y = v.y * scale[c4 + 1] + shift[c4 + 1];
    o.z = v.z * scale[c4 + 2] + shift[c4 + 2];
    o.w = v.w * scale[c4 + 3] + shift[c4 + 3];
    u16x4 hv = { f2bf(o.x), f2bf(o.y), f2bf(o.z), f2bf(o.w) };
    *reinterpret_cast<u16x4*>(&FBbf[(size_t)n * 128 + c4]) = hv;
    if (c4 >= 96) {
        float4 t = make_float4(2.f * o.x, 2.f * o.y, 2.f * o.z, 2.f * o.w);
        *reinterpret_cast<float4*>(&F[n * CCH + c4]) = t;
    }
}

// ---------------- submanifold conv: direct-fragment gather, no staging barriers ----------------
template<int KN>
__global__ __launch_bounds__(256) void conv_direct(
    const int* __restrict__ nbrA, const int* __restrict__ nbrB,
    const unsigned short* __restrict__ WBall, int wbBase,
    const unsigned short* __restrict__ FBbf,
    float* __restrict__ F, int offBase)
{
    const int which = blockIdx.y;
    const int* __restrict__ nbr = which ? nbrB : nbrA;
    const int off = offBase + which * 32;
    const unsigned short* __restrict__ WB = WBall + wbBase + which * KN * 1024;

    __shared__ __align__(16) float Ep[128 * 36];

    const int tid = threadIdx.x;
    const int wave = tid >> 6;
    const int lane = tid & 63;
    const int bm = blockIdx.x * 128;
    const int lrow = lane & 15;
    const int lk = lane >> 4;       // 0..3

    const int row0 = bm + wave * 32 + lrow;
    const int row1 = row0 + 16;

    f32x4 acc[2][2];
#pragma unroll
    for (int i = 0; i < 2; i++)
#pragma unroll
        for (int j = 0; j < 2; j++)
            acc[i][j] = (f32x4){0.f, 0.f, 0.f, 0.f};

    constexpr int CHK = (KN == 27) ? 9 : 13;
    for (int c0 = 0; c0 < KN; c0 += CHK) {
        int i0[CHK], i1[CHK];
#pragma unroll
        for (int j = 0; j < CHK; j++) {
            i0[j] = (row0 < NPTS) ? nbr[(size_t)row0 * KN + c0 + j] : NPTS;
            i1[j] = (row1 < NPTS) ? nbr[(size_t)row1 * KN + c0 + j] : NPTS;
        }
#pragma unroll
        for (int j = 0; j < CHK; j++) {
            int k = c0 + j;
            bf16x8 a0 = (bf16x8){0,0,0,0,0,0,0,0};
            bf16x8 a1 = (bf16x8){0,0,0,0,0,0,0,0};
            if (i0[j] < NPTS)
                a0 = *reinterpret_cast<const bf16x8*>(&FBbf[(size_t)i0[j] * 128 + off + lk * 8]);
            if (i1[j] < NPTS)
                a1 = *reinterpret_cast<const bf16x8*>(&FBbf[(size_t)i1[j] * 128 + off + lk * 8]);
            bf16x8 b0 = *reinterpret_cast<const bf16x8*>(&WB[k * 1024 + lrow * 32 + lk * 8]);
            bf16x8 b1 = *reinterpret_cast<const bf16x8*>(&WB[k * 1024 + (16 + lrow) * 32 + lk * 8]);
            acc[0][0] = __builtin_amdgcn_mfma_f32_16x16x32_bf16(a0, b0, acc[0][0], 0, 0, 0);
            acc[0][1] = __builtin_amdgcn_mfma_f32_16x16x32_bf16(a0, b1, acc[0][1], 0, 0, 0);
            acc[1][0] = __builtin_amdgcn_mfma_f32_16x16x32_bf16(a1, b0, acc[1][0], 0, 0, 0);
            acc[1][1] = __builtin_amdgcn_mfma_f32_16x16x32_bf16(a1, b1, acc[1][1], 0, 0, 0);
        }
    }

    // epilogue: acc -> Ep [128 pts][32 ch pad 36] -> coalesced out with residual
#pragma unroll
    for (int fi = 0; fi < 2; fi++)
#pragma unroll
        for (int fj = 0; fj < 2; fj++) {
            int r0 = wave * 32 + fi * 16 + lk * 4;
            int col = fj * 16 + lrow;
#pragma unroll
            for (int r = 0; r < 4; r++)
                Ep[(r0 + r) * 36 + col] = acc[fi][fj][r];
        }
    __syncthreads();
#pragma unroll
    for (int pass = 0; pass < 4; pass++) {
        int idx = pass * 256 + tid;
        int r = idx >> 3;
        int c4 = (idx & 7) * 4;
        int rr = bm + r;
        if (rr < NPTS) {
            float4 v = *reinterpret_cast<const float4*>(&Ep[r * 36 + c4]);
            u16x4 fbh = *reinterpret_cast<const u16x4*>(&FBbf[(size_t)rr * 128 + off + c4]);
            v.x += bf2f(fbh.x); v.y += bf2f(fbh.y);
            v.z += bf2f(fbh.z); v.w += bf2f(fbh.w);
            *reinterpret_cast<float4*>(&F[(size_t)rr * CCH + off + c4]) = v;
        }
    }
}

// ---------------- launch ----------------
extern "C" void kernel_launch(void* const* d_in, const int* in_sizes, int n_in,
                              void* d_out, int out_size, void* d_ws, size_t ws_size,
                              hipStream_t stream)
{
    const float* feats   = (const float*)d_in[0];
    const int*   win_inds= (const int*)d_in[1];
    const int*   nbr_k   = (const int*)d_in[2];
    const int*   nbr_h   = (const int*)d_in[3];
    const int*   nbr_w   = (const int*)d_in[4];
    const float* bn_g    = (const float*)d_in[5];
    const float* bn_b    = (const float*)d_in[6];
    const float* Wqkv    = (const float*)d_in[7];
    const float* Wproj   = (const float*)d_in[8];
    const float* bproj   = (const float*)d_in[9];
    const float* bn1_g   = (const float*)d_in[10];
    const float* bn1_b   = (const float*)d_in[11];
    const float* Wk      = (const float*)d_in[12];
    const float* Wh      = (const float*)d_in[13];
    const float* Ww      = (const float*)d_in[14];
    const float* bn2_g   = (const float*)d_in[15];
    const float* bn2_b   = (const float*)d_in[16];
    const float* fc1_W   = (const float*)d_in[17];
    const float* fc1_b   = (const float*)d_in[18];
    const float* fc2_W   = (const float*)d_in[19];
    const float* fc2_b   = (const float*)d_in[20];

    float* F  = (float*)d_out;
    float* KV = (float*)d_ws;                       // NWIN*2048
    float* SB = KV + NWIN * 2048;                   // NWIN*128
    float* ST = SB + NWIN * 128;                    // 6*128
    float* PART = ST + 768;                         // NBLK_STATS*256
    float* PART2 = PART + NBLK_STATS * 256;         // 16*256
    float* PKV = PART2 + 16 * 256;                  // NSEG_MAX*2176
    int* OFFS = (int*)(PKV + (size_t)NSEG_MAX * 2176);  // 256 (201 used)
    int* TOT  = OFFS + 256;                         // 256
    int* LIST = TOT + 256;                          // 100096
    int* BH   = LIST + 100096;                      // NBLK_SORT*256
    int* OFFB = BH + NBLK_SORT * 256;               // NBLK_SORT*256
    int* SEGW = OFFB + NBLK_SORT * 256;             // NSEG_MAX
    int* SEGP0= SEGW + NSEG_MAX;                    // NSEG_MAX
    int* SEGP1= SEGP0 + NSEG_MAX;                   // NSEG_MAX
    int* SEGBASE = SEGP1 + NSEG_MAX;                // 256
    unsigned short* WQKVT = (unsigned short*)(SEGBASE + 256);   // 384*128
    unsigned short* WPROJT = WQKVT + 384 * 128;                 // 128*128
    unsigned short* WFC1T  = WPROJT + 128 * 128;                // 256*128
    unsigned short* WFC2T  = WFC1T + 256 * 128;                 // 128*256
    float* BQKV  = (float*)(WFC2T + 128 * 256);     // 384
    float* BPROJ = BQKV + 384;                      // 128
    float* BFC1  = BPROJ + 128;                     // 256
    float* BFC2  = BFC1 + 256;                      // 128
    unsigned short* R0bf = (unsigned short*)(BFC2 + 128);       // NPTS*384 bf16
    unsigned short* Hbf  = R0bf;                                // aliases (fc1 after R0bf dead)
    unsigned short* Ybf  = R0bf + (size_t)NPTS * 384;           // NPTS*128
    unsigned short* FBbf = Ybf + (size_t)NPTS * 128;            // NPTS*128
    unsigned short* WBall= FBbf + (size_t)NPTS * 128;           // 53*1024

    (void)hipMemcpyAsync(F, feats, (size_t)NPTS * CCH * sizeof(float),
                         hipMemcpyDeviceToDevice, stream);

    dim3 gr(1, 1563);                   // BM=64 residual GEMMs
    dim3 gc13(782, 2);                  // h/w convs

    for (int d = 0; d < 2; d++) {
        const int* wi = win_inds + (size_t)d * NPTS;
        float* SC0 = ST, *SH0 = ST + 128, *SC1 = ST + 256, *SH1 = ST + 384,
             * SC2 = ST + 512, *SH2 = ST + 640;

        // ---- BN0 stats + folded W ----
        bn_partial<<<NBLK_STATS, 256, 0, stream>>>(F, PART);
        bnred_k<<<16, 256, 0, stream>>>(PART, PART2);
        bn_finalize<<<1, 128, 0, stream>>>(PART2, bn_g + d * CCH, bn_b + d * CCH, SC0, SH0);
        wprep<<<384, 128, 0, stream>>>(Wqkv + (size_t)d * CCH * 384, 128, 384,
                                       SC0, SH0, nullptr, WQKVT, BQKV);
        wprep<<<128, 128, 0, stream>>>(Wproj + (size_t)d * CCH * CCH, 128, 128,
                                       nullptr, nullptr, bproj + d * CCH, WPROJT, BPROJ);
        wconv_prep_all<<<212, 256, 0, stream>>>(Wk + (size_t)d * 27 * 1024,
                                                Wh + (size_t)d * 13 * 1024,
                                                Ww + (size_t)d * 13 * 1024, WBall);

        // ---- [q|k|v] = bn0(F) @ Wqkv (relu on q,k) -> R0bf (bf16, ld 384); BM=64 ----
        gemm_knt<3><<<1563, 256, 0, stream>>>(F, CCH, WQKVT, BQKV, R0bf, 384, 256);

        // ---- window lists (counting sort; parallel scans) ----
        hist2_k<<<NBLK_SORT, 256, 0, stream>>>(wi, BH);
        colscan2_k<<<NWIN, 256, 0, stream>>>(BH, OFFB, TOT);
        meta2_k<<<1, 256, 0, stream>>>(TOT, OFFS, SEGW, SEGP0, SEGP1, SEGBASE);
        scatter2_k<<<NBLK_SORT, 256, 0, stream>>>(wi, OFFS, OFFB, LIST);

        // ---- per-segment KV partials + reduce ----
        window_kv_seg<<<NSEG_MAX, 256, 0, stream>>>(R0bf, LIST, SEGP0, SEGP1, SEGBASE, PKV);
        kv_reduce<<<NWIN, 256, 0, stream>>>(PKV, SEGBASE, KV, SB);

        // ---- y (bf16) ----
        attn_y_seg<<<NSEG_MAX, 256, 0, stream>>>(R0bf, Ybf, LIST, SEGW, SEGP0, SEGP1,
                                                 SEGBASE, KV, SB);

        // ---- F += y @ Wproj + bproj (BM=64) ----
        gemm_t<1,0><<<gr, 256, 0, stream>>>(Ybf, 128, WPROJT, BPROJ, 128,
                                            F, CCH, 0, 1);

        // ---- BN1 -> FBbf (bf16, ld 128), F[:,96:] = 2*bn1(F) ----
        bn_partial<<<NBLK_STATS, 256, 0, stream>>>(F, PART);
        bnred_k<<<16, 256, 0, stream>>>(PART, PART2);
        bn_finalize<<<1, 128, 0, stream>>>(PART2, bn1_g + d * CCH, bn1_b + d * CCH, SC1, SH1);
        bn_apply<<<12500, 256, 0, stream>>>(F, FBbf, SC1, SH1);

        // ---- submanifold convs: direct-fragment gather (residual fused) ----
        conv_direct<27><<<782, 256, 0, stream>>>(nbr_k, nbr_k, WBall, 0, FBbf, F, 0);
        conv_direct<13><<<gc13, 256, 0, stream>>>(nbr_h, nbr_w, WBall, 27 * 1024, FBbf, F, 32);

        // ---- BN2 stats + folded W for fc1; fc2 prep ----
        bn_partial<<<NBLK_STATS, 256, 0, stream>>>(F, PART);
        bnred_k<<<16, 256, 0, stream>>>(PART, PART2);
        bn_finalize<<<1, 128, 0, stream>>>(PART2, bn2_g + d * CCH, bn2_b + d * CCH, SC2, SH2);
        wprep<<<256, 128, 0, stream>>>(fc1_W + (size_t)d * CCH * 256, 128, 256,
                                       SC2, SH2, fc1_b + d * 256, WFC1T, BFC1);
        wprep<<<128, 128, 0, stream>>>(fc2_W + (size_t)d * 256 * CCH, 256, 128,
                                       nullptr, nullptr, fc2_b + d * CCH, WFC2T, BFC2);

        // ---- MLP: H = relu(bn2(F) @ fc1) (bf16, BM=64); F += H @ fc2 (BM=64) ----
        gemm_knt<2><<<1563, 256, 0, stream>>>(F, CCH, WFC1T, BFC1, Hbf, 256, 256);
        gemm_t<1,0><<<gr, 256, 0, stream>>>(Hbf, 256, WFC2T, BFC2, 256,
                                            F, CCH, 0, 1);
    }
}